// Round 6
// baseline (439.315 us; speedup 1.0000x reference)
//
#include <hip/hip_runtime.h>

#define N_NODES 50000
#define N_PAD   50048                            // 782 * 64
#define N_EDGES 1600000
#define HD 128                                   // H*D = 8*16
#define EDGE4 (N_EDGES / 4)                      // 400000 uint4 packets
#define HISTB ((EDGE4 + 255) / 256)              // 1563
#define SCANB 196
#define NSCAN (SCANB * 256)                      // 50176 (>= N_NODES)
#define PROJ_BLOCKS (N_PAD / 64)                 // 782

typedef __attribute__((ext_vector_type(8))) short short8;   // 8 bf16
typedef __attribute__((ext_vector_type(4))) float floatx4;
typedef __attribute__((ext_vector_type(2))) float float2v;

union U4S8 { uint4 u; short8 s; };

// round-to-nearest-even float -> bf16 bits
__device__ __forceinline__ unsigned short f2bf(float f) {
    unsigned u = __float_as_uint(f);
    unsigned r = (u + 0x7fffu + ((u >> 16) & 1u)) >> 16;
    return (unsigned short)r;
}

// ================= hist + W-prep (fused grid) ===============================
// blocks [0,HISTB): global atomic histogram of dst -> cnt[50K] (L2-resident).
// blocks [HISTB,HISTB+24): W -> MFMA-fragment-order bf16 Wf.
__global__ __launch_bounds__(256) void k_hist(
    const int* __restrict__ dst, int* __restrict__ cnt,
    const float* __restrict__ WQ, const float* __restrict__ WK, const float* __restrict__ WV,
    unsigned short* __restrict__ Wf) {
    int t = threadIdx.x, c = blockIdx.x;
    if (c >= HISTB) {
        int tid = (c - HISTB) * 256 + t;         // 0..6143
        int lane = tid & 63;
        int kstep = (tid >> 6) & 3;
        int ntile = tid >> 8;
        int g = ntile >> 3;
        int col = (ntile & 7) * 16 + (lane & 15);
        int k0 = kstep * 32 + (lane >> 4) * 8;
        const float* W = (g == 0) ? WQ : (g == 1) ? WK : WV;
        unsigned short r[8];
#pragma unroll
        for (int j = 0; j < 8; ++j)
            r[j] = f2bf(W[(size_t)(k0 + j) * HD + col]);
        *(uint4*)(Wf + (size_t)tid * 8) = *(uint4*)r;
        return;
    }
    int i = c * 256 + t;
    if (i < EDGE4) {
        uint4 d = ((const uint4*)dst)[i];
        atomicAdd(&cnt[d.x], 1);
        atomicAdd(&cnt[d.y], 1);
        atomicAdd(&cnt[d.z], 1);
        atomicAdd(&cnt[d.w], 1);
    }
}

// ================= scan: cnt -> row_ptr (+ cur working copy) ================
__global__ __launch_bounds__(256) void k_scan(const int* __restrict__ cnt,
                                              int* __restrict__ row_ptr,
                                              int* __restrict__ cur) {
    int b = blockIdx.x, t = threadIdx.x;
    // prefix over all counts before b*256
    int x = 0;
    for (int i = t; i < b * 256; i += 256) x += cnt[i];
    __shared__ int red[256];
    red[t] = x;
    __syncthreads();
    for (int off = 128; off > 0; off >>= 1) {
        if (t < off) red[t] += red[t + off];
        __syncthreads();
    }
    int base = red[0];
    __syncthreads();
    // inclusive scan of this block's 256 counts
    int node = b * 256 + t;
    int v = (node < N_NODES) ? cnt[node] : 0;
    __shared__ int part[256];
    part[t] = v;
    __syncthreads();
    for (int off = 1; off < 256; off <<= 1) {
        int y = (t >= off) ? part[t - off] : 0;
        __syncthreads();
        part[t] += y;
        __syncthreads();
    }
    int excl = base + part[t] - v;
    if (node < N_NODES) row_ptr[node] = excl;
    if (node == N_NODES - 1) row_ptr[N_NODES] = excl + v;
    if (node < NSCAN) cur[node] = excl;
}

// ================= scatter + proj (fused grid) ==============================
// blocks [0,HISTB): direct CSR scatter — pos=atomicAdd(cur[dst]); col[pos]=src.
// blocks [HISTB,HISTB+PROJ_BLOCKS): bf16 MFMA projection (needs only Wf).
// proj writes Q (fp32, [node][128]) and interleaved KV bf16:
// KV[node][head][0..15] = K, KV[node][head][16..31] = V  (64 B per (node,head))
__global__ __launch_bounds__(256) void k_scatter_proj(
    const int* __restrict__ src, const int* __restrict__ dst,
    int* __restrict__ cur, int* __restrict__ col_src,
    const float* __restrict__ h, const unsigned short* __restrict__ Wf,
    const float* __restrict__ bQ, const float* __restrict__ bK, const float* __restrict__ bV,
    float* __restrict__ Qo, unsigned short* __restrict__ KV) {
    int c = blockIdx.x;
    int t = threadIdx.x;
    if (c >= HISTB) {
        // ---- proj path: wave owns 16 rows, loops all 24 ntiles ----
        int blk = c - HISTB;
        int w = t >> 6;          // wave 0..3
        int l = t & 63;          // lane
        int row0 = blk * 64 + w * 16;
        int arow = row0 + (l & 15);
        int akoff = (l >> 4) * 8;
        bool rowok = arow < N_NODES;

        short8 a[4];
#pragma unroll
        for (int ks = 0; ks < 4; ++ks) {
            unsigned short r[8];
            if (rowok) {
                const float4* ap = (const float4*)(h + (size_t)arow * HD + ks * 32 + akoff);
                float4 f0 = ap[0], f1 = ap[1];
                r[0] = f2bf(f0.x); r[1] = f2bf(f0.y); r[2] = f2bf(f0.z); r[3] = f2bf(f0.w);
                r[4] = f2bf(f1.x); r[5] = f2bf(f1.y); r[6] = f2bf(f1.z); r[7] = f2bf(f1.w);
            } else {
#pragma unroll
                for (int j = 0; j < 8; ++j) r[j] = 0;
            }
            a[ks] = *(short8*)r;
        }

        int orow0 = row0 + (l >> 4) * 4;   // output rows orow0..orow0+3
#pragma unroll
        for (int nt = 0; nt < 24; ++nt) {
            floatx4 acc = (floatx4){0.f, 0.f, 0.f, 0.f};
#pragma unroll
            for (int ks = 0; ks < 4; ++ks) {
                U4S8 u;
                u.u = *(const uint4*)(Wf + ((size_t)(nt * 4 + ks) * 64 + l) * 8);
                acc = __builtin_amdgcn_mfma_f32_16x16x32_bf16(a[ks], u.s, acc, 0, 0, 0);
            }
            int g = nt >> 3;
            int cc = (nt & 7) * 16 + (l & 15);
            float bias = (g == 0) ? bQ[cc] : (g == 1) ? bK[cc] : bV[cc];
            int headoff = (cc >> 4) * 32 + (cc & 15);
#pragma unroll
            for (int r = 0; r < 4; ++r) {
                int grow = orow0 + r;
                if (grow < N_NODES) {
                    float val = acc[r] + bias;
                    if (g == 0)      Qo[(size_t)grow * HD + cc] = val;
                    else if (g == 1) KV[(size_t)grow * 256 + headoff] = f2bf(val);
                    else             KV[(size_t)grow * 256 + headoff + 16] = f2bf(val);
                }
            }
        }
        return;
    }
    // ---- scatter path: one random 4B write per edge (col_src L2-resident) ---
    int i = c * 256 + t;
    if (i < EDGE4) {
        uint4 d = ((const uint4*)dst)[i];
        uint4 s = ((const uint4*)src)[i];
        int pos;
        pos = atomicAdd(&cur[d.x], 1); col_src[pos] = s.x;
        pos = atomicAdd(&cur[d.y], 1); col_src[pos] = s.y;
        pos = atomicAdd(&cur[d.z], 1); col_src[pos] = s.z;
        pos = atomicAdd(&cur[d.w], 1); col_src[pos] = s.w;
    }
}

// ================= attention: 4 nodes/block, depth-3 pipeline ===============
// (unchanged from round 5 — empirically at its memory-path bound ~105 µs)

__device__ __forceinline__ float2v bf2f2(unsigned u) {
    float2v r;
    r.x = __uint_as_float(u << 16);
    r.y = __uint_as_float(u & 0xffff0000u);
    return r;
}
#define FMA2(a, b, c) __builtin_elementwise_fma((a), (b), (c))

// load one edge's interleaved K/V for head p (unconditional, clamped slot)
#define LOADKV(K0, K1, V0, V1, blk)                                        \
    {                                                                      \
        int _b = (blk) < smax ? (blk) : smax;                              \
        int _s = __shfl(e_l, 8 * _b + o);                                  \
        const uint4* _kv = (const uint4*)(KVp + (size_t)_s * 256);         \
        K0 = _kv[0]; K1 = _kv[1]; V0 = _kv[2]; V1 = _kv[3];                \
    }

#define STEPC(K0, K1, V0, V1, blk)                                         \
    {                                                                      \
        float2v d2 = FMA2(bf2f2(K0.x), qp0, Z2);                           \
        d2 = FMA2(bf2f2(K0.y), qp1, d2);                                   \
        d2 = FMA2(bf2f2(K0.z), qp2, d2);                                   \
        d2 = FMA2(bf2f2(K0.w), qp3, d2);                                   \
        d2 = FMA2(bf2f2(K1.x), qp4, d2);                                   \
        d2 = FMA2(bf2f2(K1.y), qp5, d2);                                   \
        d2 = FMA2(bf2f2(K1.z), qp6, d2);                                   \
        d2 = FMA2(bf2f2(K1.w), qp7, d2);                                   \
        float dot = d2.x + d2.y;                                           \
        float sc = __expf(fminf(fmaxf(dot * 0.25f, -5.f), 5.f));           \
        if (8 * (blk) + o >= mm) sc = 0.f;                                 \
        float2v sc2;                                                       \
        sc2.x = sc; sc2.y = sc;                                            \
        ac0 = FMA2(sc2, bf2f2(V0.x), ac0);                                 \
        ac1 = FMA2(sc2, bf2f2(V0.y), ac1);                                 \
        ac2 = FMA2(sc2, bf2f2(V0.z), ac2);                                 \
        ac3 = FMA2(sc2, bf2f2(V0.w), ac3);                                 \
        ac4 = FMA2(sc2, bf2f2(V1.x), ac4);                                 \
        ac5 = FMA2(sc2, bf2f2(V1.y), ac5);                                 \
        ac6 = FMA2(sc2, bf2f2(V1.z), ac6);                                 \
        ac7 = FMA2(sc2, bf2f2(V1.w), ac7);                                 \
        z += sc;                                                           \
    }

__global__ __launch_bounds__(256) void attn_kernel(
    const float* __restrict__ Q,
    const unsigned short* __restrict__ KV,
    const int* __restrict__ row_ptr, const int* __restrict__ col_src,
    float* __restrict__ out) {
    int n = blockIdx.x * 4 + (threadIdx.x >> 6);
    if (n >= N_NODES) return;
    int l = threadIdx.x & 63;
    int o = l >> 3;          // octet 0..7 (edge slot)
    int p = l & 7;           // head index

    const unsigned short* KVp = KV + p * 32;

    float2v Z2;
    Z2.x = 0.f; Z2.y = 0.f;

    const float4* Qv = (const float4*)(Q + (size_t)n * HD + p * 16);
    float4 q0 = Qv[0], q1 = Qv[1], q2 = Qv[2], q3 = Qv[3];
    float2v qp0, qp1, qp2, qp3, qp4, qp5, qp6, qp7;
    qp0.x = q0.x; qp0.y = q0.y;  qp1.x = q0.z; qp1.y = q0.w;
    qp2.x = q1.x; qp2.y = q1.y;  qp3.x = q1.z; qp3.y = q1.w;
    qp4.x = q2.x; qp4.y = q2.y;  qp5.x = q2.z; qp5.y = q2.w;
    qp6.x = q3.x; qp6.y = q3.y;  qp7.x = q3.z; qp7.y = q3.w;

    float2v ac0 = Z2, ac1 = Z2, ac2 = Z2, ac3 = Z2;
    float2v ac4 = Z2, ac5 = Z2, ac6 = Z2, ac7 = Z2;
    float z = 0.f;

    int beg = row_ptr[n], end = row_ptr[n + 1];

    for (int base = beg; base < end; base += 64) {
        int mm = min(64, end - base);
        int e_l = col_src[(base + l < end) ? (base + l) : beg];
        int steps = (mm + 7) >> 3;
        int smax = steps - 1;

        uint4 xK0, xK1, xV0, xV1;
        uint4 yK0, yK1, yV0, yV1;
        uint4 zK0, zK1, zV0, zV1;

        LOADKV(xK0, xK1, xV0, xV1, 0);
        LOADKV(yK0, yK1, yV0, yV1, 1);
        LOADKV(zK0, zK1, zV0, zV1, 2);

        int i = 0;
        while (true) {
            STEPC(xK0, xK1, xV0, xV1, i);
            LOADKV(xK0, xK1, xV0, xV1, i + 3);
            if (i + 1 >= steps) break;
            STEPC(yK0, yK1, yV0, yV1, i + 1);
            LOADKV(yK0, yK1, yV0, yV1, i + 4);
            if (i + 2 >= steps) break;
            STEPC(zK0, zK1, zV0, zV1, i + 2);
            LOADKV(zK0, zK1, zV0, zV1, i + 5);
            i += 3;
            if (i >= steps) break;
        }
    }

#pragma unroll
    for (int j = 0; j < 8; ++j) {
        float2v* a = (j == 0) ? &ac0 : (j == 1) ? &ac1 : (j == 2) ? &ac2 :
                     (j == 3) ? &ac3 : (j == 4) ? &ac4 : (j == 5) ? &ac5 :
                     (j == 6) ? &ac6 : &ac7;
        a->x += __shfl_xor(a->x, 8);
        a->x += __shfl_xor(a->x, 16);
        a->x += __shfl_xor(a->x, 32);
        a->y += __shfl_xor(a->y, 8);
        a->y += __shfl_xor(a->y, 16);
        a->y += __shfl_xor(a->y, 32);
    }
    z += __shfl_xor(z, 8);
    z += __shfl_xor(z, 16);
    z += __shfl_xor(z, 32);

    if (o == 0) {
        float inv = 1.f / z;
        float4* O = (float4*)(out + (size_t)n * HD + p * 16);
        O[0] = (float4){ac0.x * inv, ac0.y * inv, ac1.x * inv, ac1.y * inv};
        O[1] = (float4){ac2.x * inv, ac2.y * inv, ac3.x * inv, ac3.y * inv};
        O[2] = (float4){ac4.x * inv, ac4.y * inv, ac5.x * inv, ac5.y * inv};
        O[3] = (float4){ac6.x * inv, ac6.y * inv, ac7.x * inv, ac7.y * inv};
    }
}

// ================= launch ===================================================

static inline char* align256(char* p) {
    return (char*)(((uintptr_t)p + 255) & ~(uintptr_t)255);
}

extern "C" void kernel_launch(void* const* d_in, const int* in_sizes, int n_in,
                              void* d_out, int out_size, void* d_ws, size_t ws_size,
                              hipStream_t stream) {
    const float* h  = (const float*)d_in[0];
    const int*   src = (const int*)d_in[1];
    const int*   dst = (const int*)d_in[2];
    const float* WQ = (const float*)d_in[3];
    const float* WK = (const float*)d_in[4];
    const float* WV = (const float*)d_in[5];
    const float* bQ = (const float*)d_in[6];
    const float* bK = (const float*)d_in[7];
    const float* bV = (const float*)d_in[8];
    float* out = (float*)d_out;

    char* p = (char*)d_ws;
    float* Q = (float*)p;                    p += (size_t)N_PAD * HD * 4;
    unsigned short* KV = (unsigned short*)p; p += (size_t)N_PAD * 256 * 2;   // interleaved K|V
    unsigned short* Wf = (unsigned short*)p; p += (size_t)24 * 4 * 64 * 8 * 2;
    p = align256(p);
    int* row_ptr = (int*)p;                  p += (N_NODES + 2) * 4;
    p = align256(p);
    int* cnt     = (int*)p;                  p += NSCAN * 4;
    p = align256(p);
    int* cur     = (int*)p;                  p += NSCAN * 4;
    p = align256(p);
    int* col_src = (int*)p;                  p += (size_t)N_EDGES * 4;

    (void)hipMemsetAsync(cnt, 0, NSCAN * sizeof(int), stream);
    k_hist<<<HISTB + 24, 256, 0, stream>>>(dst, cnt, WQ, WK, WV, Wf);
    k_scan<<<SCANB, 256, 0, stream>>>(cnt, row_ptr, cur);
    k_scatter_proj<<<HISTB + PROJ_BLOCKS, 256, 0, stream>>>(
        src, dst, cur, col_src, h, Wf, bQ, bK, bV, Q, KV);
    attn_kernel<<<(N_NODES + 3) / 4, 256, 0, stream>>>(Q, KV, row_ptr, col_src, out);
}

// Round 7
// 266.651 us; speedup vs baseline: 1.6475x; 1.6475x over previous
//
#include <hip/hip_runtime.h>

#define N_NODES 50000
#define N_PAD   50048                            // 782 * 64
#define N_EDGES 1600000
#define HD 128                                   // H*D = 8*16
#define CHUNK 4096
#define NCHUNK ((N_EDGES + CHUNK - 1) / CHUNK)   // 391
#define NBUCKET ((N_NODES + 127) / 128)          // 391 buckets of 128 nodes
#define PROJ_BLOCKS (N_PAD / 64)                 // 782

typedef __attribute__((ext_vector_type(8))) short short8;   // 8 bf16
typedef __attribute__((ext_vector_type(4))) float floatx4;
typedef __attribute__((ext_vector_type(2))) float float2v;

union U4S8 { uint4 u; short8 s; };

// round-to-nearest-even float -> bf16 bits
__device__ __forceinline__ unsigned short f2bf(float f) {
    unsigned u = __float_as_uint(f);
    unsigned r = (u + 0x7fffu + ((u >> 16) & 1u)) >> 16;
    return (unsigned short)r;
}

// ================= chunkhist + W-prep (fused grid) ==========================
__global__ __launch_bounds__(256) void k_chunkhist(
    const int* __restrict__ dst, int* __restrict__ chunkhist, int* __restrict__ btot,
    const float* __restrict__ WQ, const float* __restrict__ WK, const float* __restrict__ WV,
    unsigned short* __restrict__ Wf) {
    int t = threadIdx.x, c = blockIdx.x;
    if (c >= NCHUNK) {
        int tid = (c - NCHUNK) * 256 + t;        // 0..6143
        int lane = tid & 63;
        int kstep = (tid >> 6) & 3;
        int ntile = tid >> 8;
        int g = ntile >> 3;
        int col = (ntile & 7) * 16 + (lane & 15);
        int k0 = kstep * 32 + (lane >> 4) * 8;
        const float* W = (g == 0) ? WQ : (g == 1) ? WK : WV;
        unsigned short r[8];
#pragma unroll
        for (int j = 0; j < 8; ++j)
            r[j] = f2bf(W[(size_t)(k0 + j) * HD + col]);
        *(uint4*)(Wf + (size_t)tid * 8) = *(uint4*)r;
        return;
    }
    __shared__ int hist[NBUCKET];
    for (int i = t; i < NBUCKET; i += 256) hist[i] = 0;
    __syncthreads();
    int e0 = c * CHUNK;
    int cnt = min(CHUNK, N_EDGES - e0);
    const uint4* d4 = (const uint4*)(dst + e0);
    int cnt4 = cnt >> 2;
    for (int i = t; i < cnt4; i += 256) {
        uint4 v = d4[i];
        atomicAdd(&hist[v.x >> 7], 1);
        atomicAdd(&hist[v.y >> 7], 1);
        atomicAdd(&hist[v.z >> 7], 1);
        atomicAdd(&hist[v.w >> 7], 1);
    }
    __syncthreads();
    for (int i = t; i < NBUCKET; i += 256) {
        int v = hist[i];
        chunkhist[c * NBUCKET + i] = v;
        if (v) atomicAdd(&btot[i], v);           // fire-and-forget
    }
}

// per-(chunk,bucket) offsets; bucket base computed in-block (fused scan)
__global__ __launch_bounds__(256) void k_choff(const int* __restrict__ chunkhist,
                                               const int* __restrict__ btot,
                                               int* __restrict__ bucket_ptr,
                                               int* __restrict__ chunkoff) {
    int b = blockIdx.x, t = threadIdx.x;
    int x = 0;
    for (int i = t; i < NBUCKET; i += 256)
        if (i < b) x += btot[i];
    __shared__ int red[256];
    red[t] = x;
    __syncthreads();
    for (int off = 128; off > 0; off >>= 1) {
        if (t < off) red[t] += red[t + off];
        __syncthreads();
    }
    int base = red[0];
    if (t == 0) {
        bucket_ptr[b] = base;
        if (b == NBUCKET - 1) bucket_ptr[NBUCKET] = base + btot[b];
    }
    const int PER = (NCHUNK + 255) / 256;        // 2
    int c0 = t * PER;
    int v[PER];
    int s = 0;
#pragma unroll
    for (int i = 0; i < PER; ++i) {
        int c = c0 + i;
        v[i] = (c < NCHUNK) ? chunkhist[c * NBUCKET + b] : 0;
        s += v[i];
    }
    __shared__ int part[256];
    part[t] = s;
    __syncthreads();
    for (int off = 1; off < 256; off <<= 1) {
        int y = (t >= off) ? part[t - off] : 0;
        __syncthreads();
        part[t] += y;
        __syncthreads();
    }
    int run = base + part[t] - s;
#pragma unroll
    for (int i = 0; i < PER; ++i) {
        int c = c0 + i;
        if (c < NCHUNK) { chunkoff[c * NBUCKET + b] = run; run += v[i]; }
    }
}

// ================= scatter + proj (fused grid) ==============================
// proj writes Q (fp32, [node][128]) and interleaved KV bf16:
// KV[node][head][0..15] = K, KV[node][head][16..31] = V  (64 B per (node,head))
__global__ __launch_bounds__(256) void k_scatter_proj(
    const int* __restrict__ src, const int* __restrict__ dst,
    const int* __restrict__ chunkoff, int* __restrict__ packed,
    const float* __restrict__ h, const unsigned short* __restrict__ Wf,
    const float* __restrict__ bQ, const float* __restrict__ bK, const float* __restrict__ bV,
    float* __restrict__ Qo, unsigned short* __restrict__ KV) {
    int c = blockIdx.x;
    int t = threadIdx.x;
    if (c >= NCHUNK) {
        // ---- proj path: wave owns 16 rows, loops all 24 ntiles ----
        int blk = c - NCHUNK;
        int w = t >> 6;          // wave 0..3
        int l = t & 63;          // lane
        int row0 = blk * 64 + w * 16;
        int arow = row0 + (l & 15);
        int akoff = (l >> 4) * 8;
        bool rowok = arow < N_NODES;

        short8 a[4];
#pragma unroll
        for (int ks = 0; ks < 4; ++ks) {
            unsigned short r[8];
            if (rowok) {
                const float4* ap = (const float4*)(h + (size_t)arow * HD + ks * 32 + akoff);
                float4 f0 = ap[0], f1 = ap[1];
                r[0] = f2bf(f0.x); r[1] = f2bf(f0.y); r[2] = f2bf(f0.z); r[3] = f2bf(f0.w);
                r[4] = f2bf(f1.x); r[5] = f2bf(f1.y); r[6] = f2bf(f1.z); r[7] = f2bf(f1.w);
            } else {
#pragma unroll
                for (int j = 0; j < 8; ++j) r[j] = 0;
            }
            a[ks] = *(short8*)r;
        }

        int orow0 = row0 + (l >> 4) * 4;   // output rows orow0..orow0+3
#pragma unroll
        for (int nt = 0; nt < 24; ++nt) {
            floatx4 acc = (floatx4){0.f, 0.f, 0.f, 0.f};
#pragma unroll
            for (int ks = 0; ks < 4; ++ks) {
                U4S8 u;
                u.u = *(const uint4*)(Wf + ((size_t)(nt * 4 + ks) * 64 + l) * 8);
                acc = __builtin_amdgcn_mfma_f32_16x16x32_bf16(a[ks], u.s, acc, 0, 0, 0);
            }
            int g = nt >> 3;
            int cc = (nt & 7) * 16 + (l & 15);
            float bias = (g == 0) ? bQ[cc] : (g == 1) ? bK[cc] : bV[cc];
            int headoff = (cc >> 4) * 32 + (cc & 15);
#pragma unroll
            for (int r = 0; r < 4; ++r) {
                int grow = orow0 + r;
                if (grow < N_NODES) {
                    float val = acc[r] + bias;
                    if (g == 0)      Qo[(size_t)grow * HD + cc] = val;
                    else if (g == 1) KV[(size_t)grow * 256 + headoff] = f2bf(val);
                    else             KV[(size_t)grow * 256 + headoff + 16] = f2bf(val);
                }
            }
        }
        return;
    }
    // ---- scatter path ----
    __shared__ int cur[NBUCKET];
    for (int i = t; i < NBUCKET; i += 256) cur[i] = chunkoff[c * NBUCKET + i];
    __syncthreads();
    int e0 = c * CHUNK;
    int cnt = min(CHUNK, N_EDGES - e0);
    const uint4* d4 = (const uint4*)(dst + e0);
    const uint4* s4 = (const uint4*)(src + e0);
    int cnt4 = cnt >> 2;
    for (int i = t; i < cnt4; i += 256) {
        uint4 d = d4[i];
        uint4 s = s4[i];
        int pos;
        pos = atomicAdd(&cur[d.x >> 7], 1); packed[pos] = (s.x << 7) | (d.x & 127);
        pos = atomicAdd(&cur[d.y >> 7], 1); packed[pos] = (s.y << 7) | (d.y & 127);
        pos = atomicAdd(&cur[d.z >> 7], 1); packed[pos] = (s.z << 7) | (d.z & 127);
        pos = atomicAdd(&cur[d.w >> 7], 1); packed[pos] = (s.w << 7) | (d.w & 127);
    }
}

__global__ __launch_bounds__(256) void k_finalize(const int* __restrict__ bucket_ptr,
                                                  const int* __restrict__ packed,
                                                  int* __restrict__ row_ptr,
                                                  int* __restrict__ col_src) {
    __shared__ int hist[128], part[128], cur[128];
    int b = blockIdx.x, t = threadIdx.x;
    if (t < 128) hist[t] = 0;
    __syncthreads();
    int ebeg = bucket_ptr[b], eend = bucket_ptr[b + 1];
    int m = eend - ebeg;
    for (int i = t; i < m; i += 256)
        atomicAdd(&hist[packed[ebeg + i] & 127], 1);
    __syncthreads();
    int v = 0;
    if (t < 128) { v = hist[t]; part[t] = v; }
    __syncthreads();
    for (int off = 1; off < 128; off <<= 1) {
        int x = 0;
        if (t < 128 && t >= off) x = part[t - off];
        __syncthreads();
        if (t < 128) part[t] += x;
        __syncthreads();
    }
    if (t < 128) {
        int excl = part[t] - v;
        int node = b * 128 + t;
        if (node < N_NODES) row_ptr[node] = ebeg + excl;
        if (node == N_NODES - 1) row_ptr[N_NODES] = eend;
        cur[t] = ebeg + excl;
    }
    __syncthreads();
    for (int i = t; i < m; i += 256) {
        int p = packed[ebeg + i];
        int pos = atomicAdd(&cur[p & 127], 1);
        col_src[pos] = p >> 7;
    }
}

// ================= attention: LDS-staged gather pipeline ====================
// Depth-2 ping-pong via __builtin_amdgcn_global_load_lds: 4 gather instrs
// per 8-edge step land in a per-wave 4KB LDS buffer (no VGPR destination ->
// compiler cannot sink/collapse the pipeline). Manual counted vmcnt: issue
// step i+1 then s_waitcnt vmcnt(4) guarantees step i landed (issued-after
// counting stays correct even with compiler-tracked loads interleaved, which
// only make the wait more conservative). vmcnt(0) only at row tail, so no
// two in-flight writes ever target the same buffer.

__device__ __forceinline__ float2v bf2f2(unsigned u) {
    float2v r;
    r.x = __uint_as_float(u << 16);
    r.y = __uint_as_float(u & 0xffff0000u);
    return r;
}
#define FMA2(a, b, c) __builtin_elementwise_fma((a), (b), (c))

// issue one step's gather (8 edges x 8 heads, 64B/lane) into stage[w][par]
#define ISSUE(blk, par)                                                     \
    {                                                                       \
        int _b = (blk) < smax ? (blk) : smax;                               \
        int _s = __shfl(e_l, 8 * _b + o);                                   \
        const char* _g = KVb + ((size_t)_s << 9) + (p << 6);                \
        char* _l = (char*)&stage[w][par][0];                                \
        __builtin_amdgcn_global_load_lds(                                   \
            (const __attribute__((address_space(1))) void*)(_g),            \
            (__attribute__((address_space(3))) void*)(_l), 16, 0, 0);       \
        __builtin_amdgcn_global_load_lds(                                   \
            (const __attribute__((address_space(1))) void*)(_g + 16),       \
            (__attribute__((address_space(3))) void*)(_l + 1024), 16, 0, 0);\
        __builtin_amdgcn_global_load_lds(                                   \
            (const __attribute__((address_space(1))) void*)(_g + 32),       \
            (__attribute__((address_space(3))) void*)(_l + 2048), 16, 0, 0);\
        __builtin_amdgcn_global_load_lds(                                   \
            (const __attribute__((address_space(1))) void*)(_g + 48),       \
            (__attribute__((address_space(3))) void*)(_l + 3072), 16, 0, 0);\
    }

#define STEPC(K0, K1, V0, V1, blk)                                         \
    {                                                                      \
        float2v d2 = FMA2(bf2f2(K0.x), qp0, Z2);                           \
        d2 = FMA2(bf2f2(K0.y), qp1, d2);                                   \
        d2 = FMA2(bf2f2(K0.z), qp2, d2);                                   \
        d2 = FMA2(bf2f2(K0.w), qp3, d2);                                   \
        d2 = FMA2(bf2f2(K1.x), qp4, d2);                                   \
        d2 = FMA2(bf2f2(K1.y), qp5, d2);                                   \
        d2 = FMA2(bf2f2(K1.z), qp6, d2);                                   \
        d2 = FMA2(bf2f2(K1.w), qp7, d2);                                   \
        float dot = d2.x + d2.y;                                           \
        float sc = __expf(fminf(fmaxf(dot * 0.25f, -5.f), 5.f));           \
        if (8 * (blk) + o >= mm) sc = 0.f;                                 \
        float2v sc2;                                                       \
        sc2.x = sc; sc2.y = sc;                                            \
        ac0 = FMA2(sc2, bf2f2(V0.x), ac0);                                 \
        ac1 = FMA2(sc2, bf2f2(V0.y), ac1);                                 \
        ac2 = FMA2(sc2, bf2f2(V0.z), ac2);                                 \
        ac3 = FMA2(sc2, bf2f2(V0.w), ac3);                                 \
        ac4 = FMA2(sc2, bf2f2(V1.x), ac4);                                 \
        ac5 = FMA2(sc2, bf2f2(V1.y), ac5);                                 \
        ac6 = FMA2(sc2, bf2f2(V1.z), ac6);                                 \
        ac7 = FMA2(sc2, bf2f2(V1.w), ac7);                                 \
        z += sc;                                                           \
    }

__global__ __launch_bounds__(256) void attn_kernel(
    const float* __restrict__ Q,
    const unsigned short* __restrict__ KV,
    const int* __restrict__ row_ptr, const int* __restrict__ col_src,
    float* __restrict__ out) {
    __shared__ uint4 stage[4][2][256];           // 4 waves x 2 bufs x 4KB
    int n = blockIdx.x * 4 + (threadIdx.x >> 6);
    int w = threadIdx.x >> 6;
    int l = threadIdx.x & 63;
    int o = l >> 3;          // octet 0..7 (edge slot)
    int p = l & 7;           // head index

    const char* KVb = (const char*)KV;

    float2v Z2;
    Z2.x = 0.f; Z2.y = 0.f;

    const float4* Qv = (const float4*)(Q + (size_t)n * HD + p * 16);
    float4 q0 = Qv[0], q1 = Qv[1], q2 = Qv[2], q3 = Qv[3];
    float2v qp0, qp1, qp2, qp3, qp4, qp5, qp6, qp7;
    qp0.x = q0.x; qp0.y = q0.y;  qp1.x = q0.z; qp1.y = q0.w;
    qp2.x = q1.x; qp2.y = q1.y;  qp3.x = q1.z; qp3.y = q1.w;
    qp4.x = q2.x; qp4.y = q2.y;  qp5.x = q2.z; qp5.y = q2.w;
    qp6.x = q3.x; qp6.y = q3.y;  qp7.x = q3.z; qp7.y = q3.w;

    float2v ac0 = Z2, ac1 = Z2, ac2 = Z2, ac3 = Z2;
    float2v ac4 = Z2, ac5 = Z2, ac6 = Z2, ac7 = Z2;
    float z = 0.f;

    int beg = row_ptr[n], end = row_ptr[n + 1];

    for (int base = beg; base < end; base += 64) {
        int mm = min(64, end - base);
        int e_l = col_src[(base + l < end) ? (base + l) : beg];
        int steps = (mm + 7) >> 3;
        int smax = steps - 1;

        ISSUE(0, 0);
        for (int i = 0; i < steps; ++i) {
            int par = i & 1;
            if (i + 1 < steps) {                 // wave-uniform
                ISSUE(i + 1, par ^ 1);
                asm volatile("s_waitcnt vmcnt(4)" ::: "memory");
            } else {
                asm volatile("s_waitcnt vmcnt(0)" ::: "memory");
            }
            const uint4* sb = &stage[w][par][0];
            uint4 K0 = sb[l];
            uint4 K1 = sb[64 + l];
            uint4 V0 = sb[128 + l];
            uint4 V1 = sb[192 + l];
            STEPC(K0, K1, V0, V1, i);
        }
    }

#pragma unroll
    for (int j = 0; j < 8; ++j) {
        float2v* a = (j == 0) ? &ac0 : (j == 1) ? &ac1 : (j == 2) ? &ac2 :
                     (j == 3) ? &ac3 : (j == 4) ? &ac4 : (j == 5) ? &ac5 :
                     (j == 6) ? &ac6 : &ac7;
        a->x += __shfl_xor(a->x, 8);
        a->x += __shfl_xor(a->x, 16);
        a->x += __shfl_xor(a->x, 32);
        a->y += __shfl_xor(a->y, 8);
        a->y += __shfl_xor(a->y, 16);
        a->y += __shfl_xor(a->y, 32);
    }
    z += __shfl_xor(z, 8);
    z += __shfl_xor(z, 16);
    z += __shfl_xor(z, 32);

    if (o == 0) {
        float inv = 1.f / z;
        float4* O = (float4*)(out + (size_t)n * HD + p * 16);
        O[0] = (float4){ac0.x * inv, ac0.y * inv, ac1.x * inv, ac1.y * inv};
        O[1] = (float4){ac2.x * inv, ac2.y * inv, ac3.x * inv, ac3.y * inv};
        O[2] = (float4){ac4.x * inv, ac4.y * inv, ac5.x * inv, ac5.y * inv};
        O[3] = (float4){ac6.x * inv, ac6.y * inv, ac7.x * inv, ac7.y * inv};
    }
}

// ================= launch ===================================================

static inline char* align256(char* p) {
    return (char*)(((uintptr_t)p + 255) & ~(uintptr_t)255);
}

extern "C" void kernel_launch(void* const* d_in, const int* in_sizes, int n_in,
                              void* d_out, int out_size, void* d_ws, size_t ws_size,
                              hipStream_t stream) {
    const float* h  = (const float*)d_in[0];
    const int*   src = (const int*)d_in[1];
    const int*   dst = (const int*)d_in[2];
    const float* WQ = (const float*)d_in[3];
    const float* WK = (const float*)d_in[4];
    const float* WV = (const float*)d_in[5];
    const float* bQ = (const float*)d_in[6];
    const float* bK = (const float*)d_in[7];
    const float* bV = (const float*)d_in[8];
    float* out = (float*)d_out;

    char* p = (char*)d_ws;
    float* Q = (float*)p;                    p += (size_t)N_PAD * HD * 4;
    unsigned short* KV = (unsigned short*)p; p += (size_t)N_PAD * 256 * 2;   // interleaved K|V
    unsigned short* Wf = (unsigned short*)p; p += (size_t)24 * 4 * 64 * 8 * 2;
    p = align256(p);
    int* row_ptr    = (int*)p;               p += (N_NODES + 2) * 4;
    p = align256(p);
    int* bucket_ptr = (int*)p;               p += (NBUCKET + 1) * 4;
    p = align256(p);
    int* btot       = (int*)p;               p += NBUCKET * 4;
    p = align256(p);
    int* chunkhist  = (int*)p;               p += (size_t)NCHUNK * NBUCKET * 4;
    p = align256(p);
    int* chunkoff   = (int*)p;               p += (size_t)NCHUNK * NBUCKET * 4;
    p = align256(p);
    int* packed     = (int*)p;               p += (size_t)N_EDGES * 4;
    p = align256(p);
    int* col_src    = (int*)p;               p += (size_t)N_EDGES * 4;

    (void)hipMemsetAsync(btot, 0, NBUCKET * sizeof(int), stream);
    k_chunkhist<<<NCHUNK + 24, 256, 0, stream>>>(dst, chunkhist, btot, WQ, WK, WV, Wf);
    k_choff<<<NBUCKET, 256, 0, stream>>>(chunkhist, btot, bucket_ptr, chunkoff);
    k_scatter_proj<<<NCHUNK + PROJ_BLOCKS, 256, 0, stream>>>(
        src, dst, chunkoff, packed, h, Wf, bQ, bK, bV, Q, KV);
    k_finalize<<<NBUCKET, 256, 0, stream>>>(bucket_ptr, packed, row_ptr, col_src);
    attn_kernel<<<(N_NODES + 3) / 4, 256, 0, stream>>>(Q, KV, row_ptr, col_src, out);
}